// Round 7
// baseline (668.204 us; speedup 1.0000x reference)
//
#include <hip/hip_runtime.h>

// Fused NeRF-MLP. Round 7: CODE-SIZE collapse (I$ theory).
// Same dataflow as R6 (per-wave global_load_lds weight staging, counted
// vmcnt fences, in-register heads) but all K-loops are ROLLED
// (unroll(disable); manual x2 unroll only for static double-buffer indices).
// Hot bodies ~1KB -> I$-resident. 4096 blocks x 256 thr, 64 rows/block.

typedef __bf16 bf16x8 __attribute__((ext_vector_type(8)));
typedef float  f32x4  __attribute__((ext_vector_type(4)));
typedef short  short8 __attribute__((ext_vector_type(8)));
typedef unsigned int uint4v __attribute__((ext_vector_type(4)));

#define NROWS (8192 * 32)
#define MT 64
#define RS 260   // act row stride (520 B; 130 dw == 2 mod 32 -> uniform banks)

// packed-weight section offsets (bf16 elems); every kt is a contiguous
// 8192-elem (16KB) chunk; each wave's slice is lane-linear.
#define P0B   0        // W0^T  K=64 (pad 63)  : 2 kt
#define P1B   16384    // W1    K=256          : 8 kt
#define P2B   81920    // W2    K=512          : 16 kt
#define P3B   212992   // W3    K=512          : 16 kt
#define P4AB  344064   // W4[:256]   K=256     : 8 kt
#define P4BB  409600   // W4[256:283] K=32(27) : 1 kt
#define PTOT  417792

#define ACT_ELEMS (64 * RS)
#define SMEM_BYTES ((ACT_ELEMS + 2 * 8192) * 2 + 3072)  // 69120 -> 2 blk/CU

__device__ __forceinline__ unsigned short f2bf(float f) {
  unsigned u = __builtin_bit_cast(unsigned, f);
  u += 0x7fffu + ((u >> 16) & 1u);   // RNE
  return (unsigned short)(u >> 16);
}
__device__ __forceinline__ unsigned cvt_pk(float lo, float hi) {
  unsigned r;
  asm("v_cvt_pk_bf16_f32 %0, %1, %2" : "=v"(r) : "v"(lo), "v"(hi));
  return r;
}
__device__ __forceinline__ bf16x8 cvt8(f32x4 x, f32x4 y) {
  uint4v u;
  u[0] = cvt_pk(x[0], x[1]); u[1] = cvt_pk(x[2], x[3]);
  u[2] = cvt_pk(y[0], y[1]); u[3] = cvt_pk(y[2], y[3]);
  return __builtin_bit_cast(bf16x8, u);
}
__device__ __forceinline__ bf16x8 as_bf(short8 s) {
  return __builtin_bit_cast(bf16x8, s);
}

#define SB __builtin_amdgcn_sched_barrier(0)
#define FENCE(n) do { asm volatile("s_waitcnt vmcnt(" #n ")" ::: "memory"); SB; } while (0)
#define NOUNROLL _Pragma("clang loop unroll(disable)")

#define GLDS16(gsrc, ldst)                                                     \
  __builtin_amdgcn_global_load_lds(                                            \
      (const __attribute__((address_space(1))) unsigned int*)(gsrc),           \
      (__attribute__((address_space(3))) unsigned int*)(ldst), 16, 0, 0)

// ---------------- pre-pass: pack weights to staged fragment layout ----------
// chunk(kt) elem index bits: wv[12:11] ct[10:9] seg[8:7] l16[6:3] j[2:0]
// holds W[kt*32 + seg*8 + j][wv*64 + ct*16 + l16]
__global__ void prep_pack(const float* __restrict__ W0, const float* __restrict__ W1,
                          const float* __restrict__ W2, const float* __restrict__ W3,
                          const float* __restrict__ W4, const float* __restrict__ Wr,
                          const float* __restrict__ app, const float* __restrict__ b4,
                          unsigned short* __restrict__ pack, float* __restrict__ b4p,
                          float* __restrict__ wrT)
{
  int gid = blockIdx.x * 256 + threadIdx.x;
  if (gid < PTOT) {
    const float* W; int Kreal, base, krow = 0;
    if      (gid < P1B)  { W = W0; Kreal = 63;  base = P0B; }
    else if (gid < P2B)  { W = W1; Kreal = 256; base = P1B; }
    else if (gid < P3B)  { W = W2; Kreal = 512; base = P2B; }
    else if (gid < P4AB) { W = W3; Kreal = 512; base = P3B; }
    else if (gid < P4BB) { W = W4; Kreal = 256; base = P4AB; }
    else                 { W = W4; Kreal = 27;  base = P4BB; krow = 256; }
    int local = gid - base;
    int j   = local & 7;
    int l16 = (local >> 3) & 15;
    int seg = (local >> 7) & 3;
    int ct  = (local >> 9) & 3;
    int wv  = (local >> 11) & 3;
    int kt  = local >> 13;
    int o = wv * 64 + ct * 16 + l16;
    int k = kt * 32 + seg * 8 + j;
    float v = (k < Kreal) ? W[(long)(k + krow) * 256 + o] : 0.f;
    pack[gid] = f2bf(v);
  } else if (gid < PTOT + 256) {
    int o = gid - PTOT;
    float a = b4[o];
    for (int i = 0; i < 48; ++i) a += app[i] * W4[(long)(283 + i) * 256 + o];
    b4p[o] = a;
  } else if (gid < PTOT + 256 + 768) {
    int idx = gid - (PTOT + 256);
    int c = idx >> 8, ch = idx & 255;
    wrT[c * 256 + ch] = Wr[ch * 3 + c];
  }
}

// ---------------- main fused kernel ----------------------------------------
__global__ __launch_bounds__(256, 2)
void nerf_fused(const float* __restrict__ pos, const float* __restrict__ dirs,
                const float* __restrict__ gemo, const float* __restrict__ color,
                const float* __restrict__ mask,
                const unsigned short* __restrict__ wp,
                const float* __restrict__ b0, const float* __restrict__ b1,
                const float* __restrict__ b2, const float* __restrict__ bsv,
                const float* __restrict__ b3, const float* __restrict__ b4p,
                const float* __restrict__ brv,
                const float* __restrict__ Wsf, const float* __restrict__ wrT,
                float* __restrict__ osig, float* __restrict__ orgb)
{
  extern __shared__ unsigned short smem[];
  unsigned short* act = smem;                    // [64][RS]
  unsigned short* wst = smem + ACT_ELEMS;        // [2][8192] weight stage
  float* scr = (float*)(smem + ACT_ELEMS + 2 * 8192);  // 3 KB head scratch

  const int tid  = (int)threadIdx.x;
  const int w    = tid >> 6;
  const int lane = tid & 63;
  const int l16  = lane & 15;
  const int seg  = lane >> 4;
  const int chb  = w * 64;              // 4 disjoint 64-ch slices
  const long R0  = (long)blockIdx.x * MT;
  const int rot  = (int)(blockIdx.x & 7);

  f32x4 acc[4][4];

// stage one kt chunk: wave w's 2048-elem slice, 4x global_load_lds(16B)
#define STAGE(b, ABASE, kt)                                                    \
  {                                                                            \
    const unsigned short* s_ = wp + (ABASE) + (kt) * 8192 + w * 2048 + lane * 8; \
    unsigned short* d_ = wst + (b) * 8192 + w * 2048;                          \
    GLDS16(s_,        d_);                                                     \
    GLDS16(s_ + 512,  d_ + 512);                                               \
    GLDS16(s_ + 1024, d_ + 1024);                                              \
    GLDS16(s_ + 1536, d_ + 1536);                                              \
  }

  auto ldAs = [&](int b, int ct) -> bf16x8 {   // lane-linear, conflict-free
    return *(const bf16x8*)(wst + b * 8192 + w * 2048 +
                            ((ct * 4 + seg) * 16 + l16) * 8);
  };
  auto ldAd = [&](int baseElems, int kt, int ct) -> bf16x8 {
    return *(const bf16x8*)(wp + baseElems + kt * 8192 + w * 2048 +
                            ((ct * 4 + seg) * 16 + l16) * 8);
  };
  auto ldB_act = [&](int rt, int kt) -> bf16x8 {
    int row = rt * 16 + l16;
    return *(const bf16x8*)(act + row * RS + kt * 32 + seg * 8);
  };
  auto ldB_gen = [&](const float* __restrict__ p, int stride, int Kreal,
                     int rt, int ktl) -> bf16x8 {
    long row = R0 + rt * 16 + l16;
    const float* q = p + row * stride;
    int k0 = ktl * 32 + seg * 8;
    short8 s;
#pragma unroll
    for (int j = 0; j < 8; ++j) {
      float v = (k0 + j < Kreal) ? __builtin_nontemporal_load(q + k0 + j) : 0.0f;
      s[j] = (short)f2bf(v);
    }
    return as_bf(s);
  };
  auto initAcc = [&](const float* __restrict__ b) {
#pragma unroll
    for (int ct = 0; ct < 4; ++ct) {
      float4 bv = *(const float4*)(b + chb + ct * 16 + seg * 4);
      f32x4 t; t[0] = bv.x; t[1] = bv.y; t[2] = bv.z; t[3] = bv.w;
#pragma unroll
      for (int rt = 0; rt < 4; ++rt) acc[ct][rt] = t;
    }
  };
  auto storeAct = [&]() {
#pragma unroll
    for (int ct = 0; ct < 4; ++ct)
#pragma unroll
      for (int rt = 0; rt < 4; ++rt) {
        int row = rt * 16 + l16;
        int ch  = chb + ct * 16 + seg * 4;
        f32x4 v = acc[ct][rt];
        uint2 u;
        u.x = cvt_pk(fmaxf(v[0], 0.f), fmaxf(v[1], 0.f));
        u.y = cvt_pk(fmaxf(v[2], 0.f), fmaxf(v[3], 0.f));
        *(uint2*)(act + row * RS + ch) = u;
      }
  };

#define MFMA16(AEXPR, BFRAGS)                                                  \
  _Pragma("unroll") for (int ct = 0; ct < 4; ++ct) {                           \
    bf16x8 Af_ = (AEXPR);                                                      \
    _Pragma("unroll") for (int rt = 0; rt < 4; ++rt)                           \
      acc[ct][rt] = __builtin_amdgcn_mfma_f32_16x16x32_bf16(                   \
          Af_, BFRAGS[rt], acc[ct][rt], 0, 0, 0);                              \
  }

#define KSTEP_L(sb, kt)                                                        \
  {                                                                            \
    bf16x8 Bf_[4];                                                             \
    _Pragma("unroll") for (int rt = 0; rt < 4; ++rt) Bf_[rt] = ldB_act(rt, kt); \
    MFMA16(ldAs(sb, ct), Bf_);                                                 \
  }

#define KSTEP_G(PRE, sb)                                                       \
  {                                                                            \
    bf16x8 Bf_[4];                                                             \
    _Pragma("unroll") for (int rt = 0; rt < 4; ++rt)                           \
      Bf_[rt] = cvt8(PRE[rt][0], PRE[rt][1]);                                  \
    MFMA16(ldAs(sb, ct), Bf_);                                                 \
  }

#define BLOADV(PRE, P, ktl)                                                    \
  _Pragma("unroll") for (int rt = 0; rt < 4; ++rt) {                           \
    const f32x4* q_ = (const f32x4*)((P) + (R0 + rt * 16 + l16) * 256 +        \
                                     (ktl) * 32 + seg * 8);                    \
    PRE[rt][0] = __builtin_nontemporal_load(q_);                               \
    PRE[rt][1] = __builtin_nontemporal_load(q_ + 1);                           \
  }

// 8 staged K-steps, B from act LDS. ROLLED loop (4 iters, x2 for dbuf parity).
#define LHALF(ABASE)                                                           \
  {                                                                            \
    SB; STAGE(0, ABASE, rot);                                                  \
    NOUNROLL for (int i = 0; i < 8; i += 2) {                                  \
      SB;                                                                      \
      STAGE(1, ABASE, (i + 1 + rot) & 7); FENCE(4);                            \
      KSTEP_L(0, (i + rot) & 7);                                               \
      SB;                                                                      \
      if (i + 2 < 8) { STAGE(0, ABASE, (i + 2 + rot) & 7); FENCE(4); }         \
      else FENCE(0);                                                           \
      KSTEP_L(1, (i + 1 + rot) & 7);                                           \
    }                                                                          \
  }

// 8 staged K-steps, B streamed NT from global f32 [N,256] (distance-2 reg
// prefetch, static pre0/pre1). ROLLED loop.
#define GHALF(ABASE, P)                                                        \
  {                                                                            \
    f32x4 pre0[4][2], pre1[4][2];                                              \
    SB;                                                                        \
    STAGE(0, ABASE, 8 + rot);                                                  \
    BLOADV(pre0, P, rot);                                                      \
    BLOADV(pre1, P, (1 + rot) & 7);                                            \
    NOUNROLL for (int i = 0; i < 8; i += 2) {                                  \
      SB;                                                                      \
      STAGE(1, ABASE, 8 + ((i + 1 + rot) & 7)); FENCE(12);                     \
      KSTEP_G(pre0, 0);                                                        \
      if (i + 2 < 8) {                                                         \
        BLOADV(pre0, P, (i + 2 + rot) & 7);                                    \
        SB; STAGE(0, ABASE, 8 + ((i + 2 + rot) & 7)); FENCE(12);               \
      } else { SB; FENCE(0); }                                                 \
      KSTEP_G(pre1, 1);                                                        \
      if (i + 2 < 8) BLOADV(pre1, P, (i + 3 + rot) & 7);                       \
    }                                                                          \
  }

  // ---- L0: d0 = relu(pos @ W0 + b0) -> act
  initAcc(b0);
#pragma unroll
  for (int kt = 0; kt < 2; ++kt) {
    bf16x8 Bf_[4];
#pragma unroll
    for (int rt = 0; rt < 4; ++rt) Bf_[rt] = ldB_gen(pos, 63, 63, rt, kt);
    MFMA16(ldAd(P0B, kt, ct), Bf_);
  }
  storeAct();
  __syncthreads();

  // ---- L1: d1 = relu(d0 @ W1 + b1); act: d0 -> d1
  initAcc(b1);
  LHALF(P1B);
  __syncthreads();
  storeAct();
  __syncthreads();

  // ---- L2: d2 = [d1|gemo] @ W2 + b2 (stays in acc)
  initAcc(b2);
  GHALF(P2B, gemo);
  LHALF(P2B);

  // ---- sigma head (in-register): softplus(relu(d2) @ Ws + bs) * mask
  {
    float p[4];
#pragma unroll
    for (int rt = 0; rt < 4; ++rt) {
      float s = 0.f;
#pragma unroll
      for (int ct = 0; ct < 4; ++ct) {
        float4 w4 = *(const float4*)(Wsf + chb + ct * 16 + seg * 4);
        f32x4 a = acc[ct][rt];
        s += fmaxf(a[0], 0.f) * w4.x + fmaxf(a[1], 0.f) * w4.y +
             fmaxf(a[2], 0.f) * w4.z + fmaxf(a[3], 0.f) * w4.w;
      }
      s += __shfl_xor(s, 16);
      s += __shfl_xor(s, 32);
      p[rt] = s;
    }
    if (seg == 0) {
#pragma unroll
      for (int rt = 0; rt < 4; ++rt) scr[w * 64 + rt * 16 + l16] = p[rt];
    }
  }
  __syncthreads();
  if (tid < 64) {
    float s = scr[tid] + scr[64 + tid] + scr[128 + tid] + scr[192 + tid] + bsv[0];
    float sp = fmaxf(s, 0.f) + log1pf(expf(-fabsf(s)));
    float m = __builtin_nontemporal_load(mask + R0 + tid);
    __builtin_nontemporal_store(sp * m, osig + R0 + tid);
  }

  // ---- L3: d3 = relu([d1|color] @ W3 + b3); act: d1 -> d3
  initAcc(b3);
  GHALF(P3B, color);
  LHALF(P3B);
  __syncthreads();
  storeAct();
  __syncthreads();

  // ---- L4: d4 = [d3|dir|app] @ W4 + b4' (stays in acc)
  initAcc(b4p);
  LHALF(P4AB);
  {  // dir step (K=32, direct A)
    bf16x8 Bf_[4];
#pragma unroll
    for (int rt = 0; rt < 4; ++rt) Bf_[rt] = ldB_gen(dirs, 27, 27, rt, 0);
    MFMA16(ldAd(P4BB, 0, ct), Bf_);
  }

  // ---- rgb head (in-register): sigmoid(relu(d4) @ Wr + br)
  {
#pragma unroll
    for (int ct = 0; ct < 4; ++ct)
#pragma unroll
      for (int rt = 0; rt < 4; ++rt) {
        f32x4 a = acc[ct][rt];
        a[0] = fmaxf(a[0], 0.f); a[1] = fmaxf(a[1], 0.f);
        a[2] = fmaxf(a[2], 0.f); a[3] = fmaxf(a[3], 0.f);
        acc[ct][rt] = a;
      }
#pragma unroll
    for (int c = 0; c < 3; ++c) {
      float p[4];
#pragma unroll
      for (int rt = 0; rt < 4; ++rt) {
        float s = 0.f;
#pragma unroll
        for (int ct = 0; ct < 4; ++ct) {
          float4 w4 = *(const float4*)(wrT + c * 256 + chb + ct * 16 + seg * 4);
          f32x4 a = acc[ct][rt];
          s += a[0] * w4.x + a[1] * w4.y + a[2] * w4.z + a[3] * w4.w;
        }
        s += __shfl_xor(s, 16);
        s += __shfl_xor(s, 32);
        p[rt] = s;
      }
      if (seg == 0) {
#pragma unroll
        for (int rt = 0; rt < 4; ++rt)
          scr[c * 256 + w * 64 + rt * 16 + l16] = p[rt];
      }
    }
  }
  __syncthreads();
  if (tid < 64) {
#pragma unroll
    for (int c = 0; c < 3; ++c) {
      float s = scr[c * 256 + tid] + scr[c * 256 + 64 + tid] +
                scr[c * 256 + 128 + tid] + scr[c * 256 + 192 + tid] + brv[c];
      float r = 1.f / (1.f + expf(-s));
      __builtin_nontemporal_store(r, orgb + (R0 + tid) * 3 + c);
    }
  }
#undef STAGE
#undef MFMA16
#undef KSTEP_L
#undef KSTEP_G
#undef BLOADV
#undef LHALF
#undef GHALF
}

extern "C" void kernel_launch(void* const* d_in, const int* in_sizes, int n_in,
                              void* d_out, int out_size, void* d_ws, size_t ws_size,
                              hipStream_t stream) {
  const float* pos   = (const float*)d_in[0];
  const float* dirs  = (const float*)d_in[1];
  const float* app   = (const float*)d_in[2];
  const float* gemo  = (const float*)d_in[3];
  const float* color = (const float*)d_in[4];
  const float* mask  = (const float*)d_in[5];
  // d_in[6] = num_inters (fixed 32, shapes are static)
  const float* W0 = (const float*)d_in[7];   const float* b0 = (const float*)d_in[8];
  const float* W1 = (const float*)d_in[9];   const float* b1 = (const float*)d_in[10];
  const float* W2 = (const float*)d_in[11];  const float* b2 = (const float*)d_in[12];
  const float* Ws = (const float*)d_in[13];  const float* bs = (const float*)d_in[14];
  const float* W3 = (const float*)d_in[15];  const float* b3 = (const float*)d_in[16];
  const float* W4 = (const float*)d_in[17];  const float* b4 = (const float*)d_in[18];
  const float* Wr = (const float*)d_in[19];  const float* br = (const float*)d_in[20];

  unsigned short* pack = (unsigned short*)d_ws;
  float* b4p = (float*)((char*)d_ws + (size_t)PTOT * 2);
  float* wrT = b4p + 256;

  float* osig = (float*)d_out;
  float* orgb = osig + NROWS;

  prep_pack<<<dim3((PTOT + 256 + 768 + 255) / 256), dim3(256), 0, stream>>>(
      W0, W1, W2, W3, W4, Wr, app, b4, pack, b4p, wrT);

  hipFuncSetAttribute((const void*)nerf_fused,
                      hipFuncAttributeMaxDynamicSharedMemorySize, SMEM_BYTES);

  nerf_fused<<<dim3(NROWS / MT), dim3(256), SMEM_BYTES, stream>>>(
      pos, dirs, gemo, color, mask, pack,
      b0, b1, b2, bs, b3, b4p, br, Ws, wrT, osig, orgb);
}

// Round 8
// 453.700 us; speedup vs baseline: 1.4728x; 1.4728x over previous
//
#include <hip/hip_runtime.h>

// Fused NeRF-MLP. Round 8: pipeline the HBM STREAM (gemo/color) itself via a
// global_load_lds ring (4x8KB slots, depth-3 in flight) + counted vmcnt
// fences + raw s_barrier (no drain). Weights: direct L2 loads, SW-pipelined
// distance-2 (AfG[3]) inside sched_barrier(0)-walled regions so compiler
// A-waits (vmcnt(14)) never drain B-chunks. Thesis: R1-R7 all satisfied
// dur = FETCH/BW with BW pinned ~870 GB/s (compiler sinks reg-prefetch ->
// no MLP); glds cannot be sunk.
// 4096 blocks x 256 thr (4 waves), 64 rows/block, wave = 64ch x 64rows.

typedef __bf16 bf16x8 __attribute__((ext_vector_type(8)));
typedef float  f32x4  __attribute__((ext_vector_type(4)));
typedef short  short8 __attribute__((ext_vector_type(8)));
typedef unsigned int uint4v __attribute__((ext_vector_type(4)));

#define NROWS (8192 * 32)
#define MT 64
#define RS 260   // act row stride (520B; uniform bank spread, 0 conflicts in R7)

// packed-weight layout (bf16 elems): kt chunks of 8192 elems, lane-linear.
#define P0B   0        // W0^T  K=64 (pad 63)  : 2 kt
#define P1B   16384    // W1    K=256          : 8 kt
#define P2B   81920    // W2    K=512          : 16 kt
#define P3B   212992   // W3    K=512          : 16 kt
#define P4AB  344064   // W4[:256]   K=256     : 8 kt
#define P4BB  409600   // W4[256:283] K=32(27) : 1 kt
#define PTOT  417792

#define ACT_ELEMS (64 * RS)
// act 33280B + ring 4*8192B + scr 3072B = 69120 -> 2 blocks/CU
#define SMEM_BYTES (ACT_ELEMS * 2 + 4 * 8192 + 3072)

__device__ __forceinline__ unsigned short f2bf(float f) {
  unsigned u = __builtin_bit_cast(unsigned, f);
  u += 0x7fffu + ((u >> 16) & 1u);   // RNE
  return (unsigned short)(u >> 16);
}
__device__ __forceinline__ unsigned cvt_pk(float lo, float hi) {
  unsigned r;
  asm("v_cvt_pk_bf16_f32 %0, %1, %2" : "=v"(r) : "v"(lo), "v"(hi));
  return r;
}
__device__ __forceinline__ bf16x8 cvt8(f32x4 x, f32x4 y) {
  uint4v u;
  u[0] = cvt_pk(x[0], x[1]); u[1] = cvt_pk(x[2], x[3]);
  u[2] = cvt_pk(y[0], y[1]); u[3] = cvt_pk(y[2], y[3]);
  return __builtin_bit_cast(bf16x8, u);
}
__device__ __forceinline__ bf16x8 as_bf(short8 s) {
  return __builtin_bit_cast(bf16x8, s);
}

#define SB __builtin_amdgcn_sched_barrier(0)

#define GLDS16(gsrc, ldst)                                                     \
  __builtin_amdgcn_global_load_lds(                                            \
      (const __attribute__((address_space(1))) unsigned int*)(gsrc),           \
      (__attribute__((address_space(3))) unsigned int*)(ldst), 16, 0, 0)

// ---------------- pre-pass: pack weights to fragment layout -----------------
// chunk(kt) elem bits: wv[12:11] ct[10:9] seg[8:7] l16[6:3] j[2:0]
// holds W[kt*32 + seg*8 + j][wv*64 + ct*16 + l16]
__global__ void prep_pack(const float* __restrict__ W0, const float* __restrict__ W1,
                          const float* __restrict__ W2, const float* __restrict__ W3,
                          const float* __restrict__ W4, const float* __restrict__ Wr,
                          const float* __restrict__ app, const float* __restrict__ b4,
                          unsigned short* __restrict__ pack, float* __restrict__ b4p,
                          float* __restrict__ wrT)
{
  int gid = blockIdx.x * 256 + threadIdx.x;
  if (gid < PTOT) {
    const float* W; int Kreal, base, krow = 0;
    if      (gid < P1B)  { W = W0; Kreal = 63;  base = P0B; }
    else if (gid < P2B)  { W = W1; Kreal = 256; base = P1B; }
    else if (gid < P3B)  { W = W2; Kreal = 512; base = P2B; }
    else if (gid < P4AB) { W = W3; Kreal = 512; base = P3B; }
    else if (gid < P4BB) { W = W4; Kreal = 256; base = P4AB; }
    else                 { W = W4; Kreal = 27;  base = P4BB; krow = 256; }
    int local = gid - base;
    int j   = local & 7;
    int l16 = (local >> 3) & 15;
    int seg = (local >> 7) & 3;
    int ct  = (local >> 9) & 3;
    int wv  = (local >> 11) & 3;
    int kt  = local >> 13;
    int o = wv * 64 + ct * 16 + l16;
    int k = kt * 32 + seg * 8 + j;
    float v = (k < Kreal) ? W[(long)(k + krow) * 256 + o] : 0.f;
    pack[gid] = f2bf(v);
  } else if (gid < PTOT + 256) {
    int o = gid - PTOT;
    float a = b4[o];
    for (int i = 0; i < 48; ++i) a += app[i] * W4[(long)(283 + i) * 256 + o];
    b4p[o] = a;
  } else if (gid < PTOT + 256 + 768) {
    int idx = gid - (PTOT + 256);
    int c = idx >> 8, ch = idx & 255;
    wrT[c * 256 + ch] = Wr[ch * 3 + c];
  }
}

// ---------------- main fused kernel ----------------------------------------
__global__ __launch_bounds__(256, 2)
void nerf_fused(const float* __restrict__ pos, const float* __restrict__ dirs,
                const float* __restrict__ gemo, const float* __restrict__ color,
                const float* __restrict__ mask,
                const unsigned short* __restrict__ wp,
                const float* __restrict__ b0, const float* __restrict__ b1,
                const float* __restrict__ b2, const float* __restrict__ bsv,
                const float* __restrict__ b3, const float* __restrict__ b4p,
                const float* __restrict__ brv,
                const float* __restrict__ Wsf, const float* __restrict__ wrT,
                float* __restrict__ osig, float* __restrict__ orgb)
{
  extern __shared__ unsigned short smem[];
  unsigned short* act  = smem;                       // [64][RS] bf16
  unsigned short* ring = smem + ACT_ELEMS;           // 4 slots x 8KB raw f32
  float* scr = (float*)(smem + ACT_ELEMS + 4 * 4096);  // 3 KB head scratch

  const int tid  = (int)threadIdx.x;
  const int w    = tid >> 6;
  const int lane = tid & 63;
  const int l16  = lane & 15;
  const int seg  = lane >> 4;
  const int chb  = w * 64;              // 4 disjoint 64-ch slices
  const long R0  = (long)blockIdx.x * MT;
  const int rot  = (int)(blockIdx.x & 7);

  f32x4 acc[4][4];

  // stage one 8KB B-chunk (rows 0..63 x 32 f32 cols) cooperatively:
  // 2 glds per wave; unit u = m*256 + w*64 + lane holds (row=u>>3,
  // part=(u&7)^(row&7)) -> XOR-swizzled for conflict-free b128 reads.
  auto stageB = [&](const float* __restrict__ P, int slot, int c) {
#pragma unroll
    for (int m = 0; m < 2; ++m) {
      int u = m * 256 + w * 64 + lane;
      int row = u >> 3;
      int part = (u & 7) ^ (row & 7);
      const float* src = P + (R0 + row) * 256 + c * 32 + part * 4;
      unsigned short* dst = ring + slot * 4096 + (m * 256 + w * 64) * 8;
      GLDS16(src, dst);
    }
  };
  auto ldB_ring = [&](int slot, int rt, int p) -> f32x4 {
    int row = rt * 16 + l16;
    return *(const f32x4*)(ring + slot * 4096 + (row * 8 + (p ^ (row & 7))) * 8);
  };
  auto ldAd = [&](int baseElems, int kt, int ct) -> bf16x8 {
    return *(const bf16x8*)(wp + baseElems + kt * 8192 + w * 2048 +
                            ((ct * 4 + seg) * 16 + l16) * 8);
  };
  auto ldB_act = [&](int rt, int kt) -> bf16x8 {
    int row = rt * 16 + l16;
    return *(const bf16x8*)(act + row * RS + kt * 32 + seg * 8);
  };
  auto ldB_gen = [&](const float* __restrict__ p, int stride, int Kreal,
                     int rt, int ktl) -> bf16x8 {
    long row = R0 + rt * 16 + l16;
    const float* q = p + row * stride;
    int k0 = ktl * 32 + seg * 8;
    short8 s;
#pragma unroll
    for (int j = 0; j < 8; ++j) {
      float v = (k0 + j < Kreal) ? __builtin_nontemporal_load(q + k0 + j) : 0.0f;
      s[j] = (short)f2bf(v);
    }
    return as_bf(s);
  };
  auto initAcc = [&](const float* __restrict__ b) {
#pragma unroll
    for (int ct = 0; ct < 4; ++ct) {
      float4 bv = *(const float4*)(b + chb + ct * 16 + seg * 4);
      f32x4 t; t[0] = bv.x; t[1] = bv.y; t[2] = bv.z; t[3] = bv.w;
#pragma unroll
      for (int rt = 0; rt < 4; ++rt) acc[ct][rt] = t;
    }
  };
  auto storeAct = [&]() {
#pragma unroll
    for (int ct = 0; ct < 4; ++ct)
#pragma unroll
      for (int rt = 0; rt < 4; ++rt) {
        int row = rt * 16 + l16;
        int ch  = chb + ct * 16 + seg * 4;
        f32x4 v = acc[ct][rt];
        uint2 u;
        u.x = cvt_pk(fmaxf(v[0], 0.f), fmaxf(v[1], 0.f));
        u.y = cvt_pk(fmaxf(v[2], 0.f), fmaxf(v[3], 0.f));
        *(uint2*)(act + row * RS + ch) = u;
      }
  };

#define MFMA16(AEXPR, BFRAGS)                                                  \
  _Pragma("unroll") for (int ct = 0; ct < 4; ++ct) {                           \
    bf16x8 Af_ = (AEXPR);                                                      \
    _Pragma("unroll") for (int rt = 0; rt < 4; ++rt)                           \
      acc[ct][rt] = __builtin_amdgcn_mfma_f32_16x16x32_bf16(                   \
          Af_, BFRAGS[rt], acc[ct][rt], 0, 0, 0);                              \
  }

// 8 K-steps, B from act LDS, A direct L2 (compiler-scheduled).
#define LHALF(ABASE)                                                           \
  _Pragma("unroll") for (int i = 0; i < 8; ++i) {                              \
    int kt = (i + rot) & 7;                                                    \
    bf16x8 Bf_[4];                                                             \
    _Pragma("unroll") for (int rt = 0; rt < 4; ++rt) Bf_[rt] = ldB_act(rt, kt); \
    MFMA16(ldAd(ABASE, kt, ct), Bf_);                                          \
  }

// One stream step. Region order fixes the vmcnt ledger:
// [FENCE(N)][bar][A(i+2)->AfG][stage(i+3)][B-read+cvt][MFMA(i)]
// steady state: ops issued after chunk i = A(i)4+st(i+1)2+A(i+1)4+st(i+2)2
// = 12 -> FENCE(12) drains exactly chunk i; tail: 10, 4.
#define GREG(i, NFENCE)                                                        \
  {                                                                            \
    asm volatile("s_waitcnt vmcnt(" #NFENCE ")" ::: "memory");                 \
    SB;                                                                        \
    __builtin_amdgcn_s_barrier();                                              \
    if ((i) + 2 < 8) {                                                         \
      _Pragma("unroll") for (int ct = 0; ct < 4; ++ct)                         \
        AfG[((i) + 2) % 3][ct] = ldAd(GABASE, 8 + (((i) + 2 + rot) & 7), ct);  \
    }                                                                          \
    if ((i) + 3 < 8) stageB(GP, ((i) + 3) & 3, ((i) + 3 + rot) & 7);           \
    SB;                                                                        \
    bf16x8 Bf_[4];                                                             \
    _Pragma("unroll") for (int rt = 0; rt < 4; ++rt) {                         \
      f32x4 lo = ldB_ring((i) & 3, rt, 2 * seg);                               \
      f32x4 hi = ldB_ring((i) & 3, rt, 2 * seg + 1);                           \
      Bf_[rt] = cvt8(lo, hi);                                                  \
    }                                                                          \
    _Pragma("unroll") for (int ct = 0; ct < 4; ++ct) {                         \
      _Pragma("unroll") for (int rt = 0; rt < 4; ++rt)                         \
        acc[ct][rt] = __builtin_amdgcn_mfma_f32_16x16x32_bf16(                 \
            AfG[(i) % 3][ct], Bf_[rt], acc[ct][rt], 0, 0, 0);                  \
    }                                                                          \
  }

#define GHALF(ABASE, P)                                                        \
  {                                                                            \
    const int GABASE = (ABASE); const float* __restrict__ GP = (P);            \
    bf16x8 AfG[3][4];                                                          \
    SB;                                                                        \
    _Pragma("unroll") for (int ct = 0; ct < 4; ++ct) {                         \
      AfG[0][ct] = ldAd(GABASE, 8 + ((0 + rot) & 7), ct);                      \
      AfG[1][ct] = ldAd(GABASE, 8 + ((1 + rot) & 7), ct);                      \
    }                                                                          \
    SB;                                                                        \
    GREG(0, 12) GREG(1, 12) GREG(2, 12) GREG(3, 12)                            \
    GREG(4, 12) GREG(5, 12) GREG(6, 10) GREG(7, 4)                             \
  }

  // ---- L0: d0 = relu(pos @ W0 + b0) -> act
  initAcc(b0);
#pragma unroll
  for (int kt = 0; kt < 2; ++kt) {
    bf16x8 Bf_[4];
#pragma unroll
    for (int rt = 0; rt < 4; ++rt) Bf_[rt] = ldB_gen(pos, 63, 63, rt, kt);
    MFMA16(ldAd(P0B, kt, ct), Bf_);
  }
  storeAct();
  __syncthreads();

  // ---- L1: d1 = relu(d0 @ W1 + b1); act: d0 -> d1
  initAcc(b1);
  LHALF(P1B);
  __syncthreads();
  storeAct();
  __syncthreads();

  // ---- L2: d2 = [d1|gemo] @ W2 + b2 (stays in acc)
  // ring prolog first: gemo chunks 0..2 fly during LHALF's 8 steps
  stageB(gemo, 0, rot);
  stageB(gemo, 1, (1 + rot) & 7);
  stageB(gemo, 2, (2 + rot) & 7);
  initAcc(b2);
  LHALF(P2B);
  GHALF(P2B, gemo);

  // ---- sigma head (in-register): softplus(relu(d2) @ Ws + bs) * mask
  {
    float p[4];
#pragma unroll
    for (int rt = 0; rt < 4; ++rt) {
      float s = 0.f;
#pragma unroll
      for (int ct = 0; ct < 4; ++ct) {
        float4 w4 = *(const float4*)(Wsf + chb + ct * 16 + seg * 4);
        f32x4 a = acc[ct][rt];
        s += fmaxf(a[0], 0.f) * w4.x + fmaxf(a[1], 0.f) * w4.y +
             fmaxf(a[2], 0.f) * w4.z + fmaxf(a[3], 0.f) * w4.w;
      }
      s += __shfl_xor(s, 16);
      s += __shfl_xor(s, 32);
      p[rt] = s;
    }
    if (seg == 0) {
#pragma unroll
      for (int rt = 0; rt < 4; ++rt) scr[w * 64 + rt * 16 + l16] = p[rt];
    }
  }
  __syncthreads();
  if (tid < 64) {
    float s = scr[tid] + scr[64 + tid] + scr[128 + tid] + scr[192 + tid] + bsv[0];
    float sp = fmaxf(s, 0.f) + log1pf(expf(-fabsf(s)));
    float m = __builtin_nontemporal_load(mask + R0 + tid);
    __builtin_nontemporal_store(sp * m, osig + R0 + tid);
  }

  // ---- L3: d3 = relu([d1|color] @ W3 + b3); act: d1 -> d3
  stageB(color, 0, rot);
  stageB(color, 1, (1 + rot) & 7);
  stageB(color, 2, (2 + rot) & 7);
  initAcc(b3);
  LHALF(P3B);
  GHALF(P3B, color);
  __syncthreads();
  storeAct();
  __syncthreads();

  // ---- L4: d4 = [d3|dir|app] @ W4 + b4' (stays in acc)
  initAcc(b4p);
  LHALF(P4AB);
  {  // dir step (K=32, direct A)
    bf16x8 Bf_[4];
#pragma unroll
    for (int rt = 0; rt < 4; ++rt) Bf_[rt] = ldB_gen(dirs, 27, 27, rt, 0);
    MFMA16(ldAd(P4BB, 0, ct), Bf_);
  }

  // ---- rgb head (in-register): sigmoid(relu(d4) @ Wr + br)
  {
#pragma unroll
    for (int ct = 0; ct < 4; ++ct)
#pragma unroll
      for (int rt = 0; rt < 4; ++rt) {
        f32x4 a = acc[ct][rt];
        a[0] = fmaxf(a[0], 0.f); a[1] = fmaxf(a[1], 0.f);
        a[2] = fmaxf(a[2], 0.f); a[3] = fmaxf(a[3], 0.f);
        acc[ct][rt] = a;
      }
#pragma unroll
    for (int c = 0; c < 3; ++c) {
      float p[4];
#pragma unroll
      for (int rt = 0; rt < 4; ++rt) {
        float s = 0.f;
#pragma unroll
        for (int ct = 0; ct < 4; ++ct) {
          float4 w4 = *(const float4*)(wrT + c * 256 + chb + ct * 16 + seg * 4);
          f32x4 a = acc[ct][rt];
          s += a[0] * w4.x + a[1] * w4.y + a[2] * w4.z + a[3] * w4.w;
        }
        s += __shfl_xor(s, 16);
        s += __shfl_xor(s, 32);
        p[rt] = s;
      }
      if (seg == 0) {
#pragma unroll
        for (int rt = 0; rt < 4; ++rt)
          scr[c * 256 + w * 64 + rt * 16 + l16] = p[rt];
      }
    }
  }
  __syncthreads();
  if (tid < 64) {
#pragma unroll
    for (int c = 0; c < 3; ++c) {
      float s = scr[c * 256 + tid] + scr[c * 256 + 64 + tid] +
                scr[c * 256 + 128 + tid] + scr[c * 256 + 192 + tid] + brv[c];
      float r = 1.f / (1.f + expf(-s));
      __builtin_nontemporal_store(r, orgb + (R0 + tid) * 3 + c);
    }
  }
#undef MFMA16
#undef LHALF
#undef GREG
#undef GHALF
}

extern "C" void kernel_launch(void* const* d_in, const int* in_sizes, int n_in,
                              void* d_out, int out_size, void* d_ws, size_t ws_size,
                              hipStream_t stream) {
  const float* pos   = (const float*)d_in[0];
  const float* dirs  = (const float*)d_in[1];
  const float* app   = (const float*)d_in[2];
  const float* gemo  = (const float*)d_in[3];
  const float* color = (const float*)d_in[4];
  const float* mask  = (const float*)d_in[5];
  // d_in[6] = num_inters (fixed 32, shapes are static)
  const float* W0 = (const float*)d_in[7];   const float* b0 = (const float*)d_in[8];
  const float* W1 = (const float*)d_in[9];   const float* b1 = (const float*)d_in[10];
  const float* W2 = (const float*)d_in[11];  const float* b2 = (const float*)d_in[12];
  const float* Ws = (const float*)d_in[13];  const float* bs = (const float*)d_in[14];
  const float* W3 = (const float*)d_in[15];  const float* b3 = (const float*)d_in[16];
  const float* W4 = (const float*)d_in[17];  const float* b4 = (const float*)d_in[18];
  const float* Wr = (const float*)d_in[19];  const float* br = (const float*)d_in[20];

  unsigned short* pack = (unsigned short*)d_ws;
  float* b4p = (float*)((char*)d_ws + (size_t)PTOT * 2);
  float* wrT = b4p + 256;

  float* osig = (float*)d_out;
  float* orgb = osig + NROWS;

  prep_pack<<<dim3((PTOT + 256 + 768 + 255) / 256), dim3(256), 0, stream>>>(
      W0, W1, W2, W3, W4, Wr, app, b4, pack, b4p, wrT);

  hipFuncSetAttribute((const void*)nerf_fused,
                      hipFuncAttributeMaxDynamicSharedMemorySize, SMEM_BYTES);

  nerf_fused<<<dim3(NROWS / MT), dim3(256), SMEM_BYTES, stream>>>(
      pos, dirs, gemo, color, mask, pack,
      b0, b1, b2, bs, b3, b4p, br, Ws, wrT, osig, orgb);
}